// Round 3
// baseline (150.779 us; speedup 1.0000x reference)
//
#include <hip/hip_runtime.h>
#include <hip/hip_bf16.h>

// Problem: B=32, L=512, D=1024, R=128
//   t = batch(16384x1024) @ proj(1024x128)          [bf16 MFMA, fp32 acc]
//   d[b,i,j] = ||t_i||^2 + ||t_j||^2 - 2 t_i.t_j,  clamp >= 0
//
// R3 design: barrier-free K-loops + EXPLICIT register double-buffering.
// R2's failure: VGPR_Count=44 forced load->waitcnt->use serialization
// (MfmaUtil 3%, all pipes idle). Two named stages (X/Y) force the compiler
// to keep iter k+1's loads in flight while iter k computes.

typedef __attribute__((ext_vector_type(8))) short bf16x8;
typedef __attribute__((ext_vector_type(4))) float f32x4;

__device__ __forceinline__ unsigned short f2bf(float f) {
    unsigned u = __float_as_uint(f);
    unsigned r = (u + 0x7fffu + ((u >> 16) & 1u)) >> 16;   // RNE
    return (unsigned short)r;
}
__device__ __forceinline__ float bf2f(unsigned short h) {
    return __uint_as_float(((unsigned)h) << 16);
}
__device__ __forceinline__ bf16x8 pack8(float4 x, float4 y) {
    bf16x8 r;
    r[0] = (short)f2bf(x.x); r[1] = (short)f2bf(x.y);
    r[2] = (short)f2bf(x.z); r[3] = (short)f2bf(x.w);
    r[4] = (short)f2bf(y.x); r[5] = (short)f2bf(y.y);
    r[6] = (short)f2bf(y.z); r[7] = (short)f2bf(y.w);
    return r;
}

// ---------------- kernel 0: proj (1024x128 f32) -> projT (128x1024 bf16) ----------------
__global__ __launch_bounds__(256) void transpose_proj(const float* __restrict__ proj,
                                                      unsigned short* __restrict__ projT) {
    __shared__ unsigned short TsT[128][40];
    const int k0 = blockIdx.x * 32;
    const int t = threadIdx.x;
    const int kl = t >> 3;
    const int seg = t & 7;
    const float* src = proj + (k0 + kl) * 128 + seg * 16;
#pragma unroll
    for (int i = 0; i < 4; ++i) {
        float4 v = *(const float4*)(src + 4 * i);
        int c = seg * 16 + 4 * i;
        TsT[c + 0][kl] = f2bf(v.x);
        TsT[c + 1][kl] = f2bf(v.y);
        TsT[c + 2][kl] = f2bf(v.z);
        TsT[c + 3][kl] = f2bf(v.w);
    }
    __syncthreads();
    const int r = t >> 1, h = t & 1;
#pragma unroll
    for (int i = 0; i < 2; ++i) {
        *(uint4*)(projT + r * 1024 + k0 + h * 16 + 8 * i) =
            *(const uint4*)&TsT[r][h * 16 + 8 * i];
    }
}

// ---------------- kernel 1: t = batch @ proj  (M=16384, N=128, K=1024) ----------------
// grid 512 (M-tile 32), block 256 = 4 waves (2M x 2N). Register double-buffered
// K-loop, no LDS, no barriers until the sqn epilogue.
__global__ __launch_bounds__(256, 2) void gemm_t(const float* __restrict__ batch,
                                                 const unsigned short* __restrict__ projT,
                                                 unsigned short* __restrict__ tOut,
                                                 float* __restrict__ sqn) {
    __shared__ float sqpart[2][2][16];

    const int t = threadIdx.x;
    const int wave = t >> 6, lane = t & 63;
    const int wm = wave >> 1, wn = wave & 1;
    const int quad = lane >> 4, l15 = lane & 15;
    const int m0 = blockIdx.x * 32;

    f32x4 acc[4] = {};
    const float* aptr = batch + (m0 + wm * 16 + l15) * 1024 + quad * 8;
    const unsigned short* bbase = projT + (wn * 64 + l15) * 1024 + quad * 8;

    // two explicit pipeline stages
    float4 xa0, xa1, xa2, xa3; bf16x8 xb[8];
    float4 ya0, ya1, ya2, ya3; bf16x8 yb[8];

    auto loadX = [&](int kk) {
        xa0 = *(const float4*)(aptr + kk);
        xa1 = *(const float4*)(aptr + kk + 4);
        xa2 = *(const float4*)(aptr + kk + 32);
        xa3 = *(const float4*)(aptr + kk + 36);
#pragma unroll
        for (int fn = 0; fn < 4; ++fn) {
            xb[fn]     = *(const bf16x8*)(bbase + fn * 16 * 1024 + kk);
            xb[fn + 4] = *(const bf16x8*)(bbase + fn * 16 * 1024 + kk + 32);
        }
    };
    auto loadY = [&](int kk) {
        ya0 = *(const float4*)(aptr + kk);
        ya1 = *(const float4*)(aptr + kk + 4);
        ya2 = *(const float4*)(aptr + kk + 32);
        ya3 = *(const float4*)(aptr + kk + 36);
#pragma unroll
        for (int fn = 0; fn < 4; ++fn) {
            yb[fn]     = *(const bf16x8*)(bbase + fn * 16 * 1024 + kk);
            yb[fn + 4] = *(const bf16x8*)(bbase + fn * 16 * 1024 + kk + 32);
        }
    };
    auto computeX = [&]() {
        bf16x8 af0 = pack8(xa0, xa1);
        bf16x8 af1 = pack8(xa2, xa3);
#pragma unroll
        for (int fn = 0; fn < 4; ++fn)
            acc[fn] = __builtin_amdgcn_mfma_f32_16x16x32_bf16(af0, xb[fn], acc[fn], 0, 0, 0);
#pragma unroll
        for (int fn = 0; fn < 4; ++fn)
            acc[fn] = __builtin_amdgcn_mfma_f32_16x16x32_bf16(af1, xb[fn + 4], acc[fn], 0, 0, 0);
    };
    auto computeY = [&]() {
        bf16x8 af0 = pack8(ya0, ya1);
        bf16x8 af1 = pack8(ya2, ya3);
#pragma unroll
        for (int fn = 0; fn < 4; ++fn)
            acc[fn] = __builtin_amdgcn_mfma_f32_16x16x32_bf16(af0, yb[fn], acc[fn], 0, 0, 0);
#pragma unroll
        for (int fn = 0; fn < 4; ++fn)
            acc[fn] = __builtin_amdgcn_mfma_f32_16x16x32_bf16(af1, yb[fn + 4], acc[fn], 0, 0, 0);
    };

    loadX(0);
#pragma unroll
    for (int kk = 0; kk < 1024; kk += 128) {
        loadY(kk + 64);            // stage k+1 in flight before consuming stage k
        computeX();
        loadX((kk + 128) & 1023);  // last one wraps to 0 (wasted but branch-free)
        computeY();
    }

    // epilogue: write t (bf16), accumulate row sq-norms from ROUNDED values
    float p[4] = {0.f, 0.f, 0.f, 0.f};
#pragma unroll
    for (int fn = 0; fn < 4; ++fn) {
        int col = wn * 64 + fn * 16 + l15;
#pragma unroll
        for (int reg = 0; reg < 4; ++reg) {
            int row = m0 + wm * 16 + quad * 4 + reg;
            unsigned short hb = f2bf(acc[fn][reg]);
            tOut[row * 128 + col] = hb;
            float fv = bf2f(hb);
            p[reg] += fv * fv;
        }
    }
#pragma unroll
    for (int off = 1; off < 16; off <<= 1) {
#pragma unroll
        for (int reg = 0; reg < 4; ++reg) p[reg] += __shfl_xor(p[reg], off);
    }
    if (l15 == 0) {
#pragma unroll
        for (int reg = 0; reg < 4; ++reg) sqpart[wm][wn][quad * 4 + reg] = p[reg];
    }
    __syncthreads();
    if (t < 32) {
        int wmi = t >> 4, ridx = t & 15;
        sqn[m0 + wmi * 16 + ridx] = sqpart[wmi][0][ridx] + sqpart[wmi][1][ridx];
    }
}

// ---------------- kernel 2: d[b,i,j] = sq_i + sq_j - 2 * t_i . t_j, clamped ----------------
// grid 512 = 32 batches x 4x4 tiles of 128. Transposed tile (A=t_j, B=t_i) ->
// float4 stores. B-fragment loads pipelined one k-step ahead.
__global__ __launch_bounds__(256, 2) void dist_k(const unsigned short* __restrict__ tMat,
                                                 const float* __restrict__ sqn,
                                                 float* __restrict__ out) {
    const int bx = blockIdx.x;
    const int b = bx >> 4, it = (bx >> 2) & 3, jt = bx & 3;
    const int i0 = it * 128, j0 = jt * 128;
    const int t = threadIdx.x;
    const int wave = t >> 6, lane = t & 63;
    const int quad = lane >> 4, l15 = lane & 15;

    // A fragments: j-rows, prefetched up-front (16 loads in flight)
    const unsigned short* abase = tMat + (b * 512 + j0 + wave * 32 + l15) * 128 + quad * 8;
    uint4 araw[2][4];
#pragma unroll
    for (int fm = 0; fm < 2; ++fm)
#pragma unroll
        for (int ksi = 0; ksi < 4; ++ksi)
            araw[fm][ksi] = *(const uint4*)(abase + fm * 16 * 128 + ksi * 32);

    const float* sqb = sqn + b * 512;
    float sqj_[2][4], sqi_[8];
#pragma unroll
    for (int fm = 0; fm < 2; ++fm)
#pragma unroll
        for (int reg = 0; reg < 4; ++reg)
            sqj_[fm][reg] = sqb[j0 + wave * 32 + fm * 16 + quad * 4 + reg];
#pragma unroll
    for (int fn = 0; fn < 8; ++fn)
        sqi_[fn] = sqb[i0 + fn * 16 + l15];

    const unsigned short* bbase = tMat + (b * 512 + i0 + l15) * 128 + quad * 8;

    bf16x8 xb[8], yb[8];
    auto loadBX = [&](int ksi) {
#pragma unroll
        for (int fn = 0; fn < 8; ++fn)
            xb[fn] = *(const bf16x8*)(bbase + fn * 16 * 128 + ksi * 32);
    };
    auto loadBY = [&](int ksi) {
#pragma unroll
        for (int fn = 0; fn < 8; ++fn)
            yb[fn] = *(const bf16x8*)(bbase + fn * 16 * 128 + ksi * 32);
    };

    f32x4 acc[2][8] = {};
    auto computeX = [&](int ksi) {
#pragma unroll
        for (int fm = 0; fm < 2; ++fm) {
            bf16x8 af = *(const bf16x8*)&araw[fm][ksi];
#pragma unroll
            for (int fn = 0; fn < 8; ++fn)
                acc[fm][fn] = __builtin_amdgcn_mfma_f32_16x16x32_bf16(af, xb[fn], acc[fm][fn], 0, 0, 0);
        }
    };
    auto computeY = [&](int ksi) {
#pragma unroll
        for (int fm = 0; fm < 2; ++fm) {
            bf16x8 af = *(const bf16x8*)&araw[fm][ksi];
#pragma unroll
            for (int fn = 0; fn < 8; ++fn)
                acc[fm][fn] = __builtin_amdgcn_mfma_f32_16x16x32_bf16(af, yb[fn], acc[fm][fn], 0, 0, 0);
        }
    };

    loadBX(0);
    loadBY(1); computeX(0);
    loadBX(2); computeY(1);
    loadBY(3); computeX(2);
    computeY(3);

    // epilogue: d = sq_i + sq_j - 2c, clamp, float4 stores (j-contiguous)
    float* obase = out + (size_t)b * 512 * 512;
#pragma unroll
    for (int fn = 0; fn < 8; ++fn) {
        const int i = i0 + fn * 16 + l15;
        float* orow = obase + (size_t)i * 512 + j0;
        const float si = sqi_[fn];
#pragma unroll
        for (int fm = 0; fm < 2; ++fm) {
            float4 v;
            v.x = fmaxf(si + sqj_[fm][0] - 2.0f * acc[fm][fn][0], 0.0f);
            v.y = fmaxf(si + sqj_[fm][1] - 2.0f * acc[fm][fn][1], 0.0f);
            v.z = fmaxf(si + sqj_[fm][2] - 2.0f * acc[fm][fn][2], 0.0f);
            v.w = fmaxf(si + sqj_[fm][3] - 2.0f * acc[fm][fn][3], 0.0f);
            *(float4*)(orow + wave * 32 + fm * 16 + quad * 4) = v;
        }
    }
}

extern "C" void kernel_launch(void* const* d_in, const int* in_sizes, int n_in,
                              void* d_out, int out_size, void* d_ws, size_t ws_size,
                              hipStream_t stream) {
    (void)in_sizes; (void)n_in; (void)out_size; (void)ws_size;
    const float* batch = (const float*)d_in[0];
    const float* proj  = (const float*)d_in[1];
    float* out = (float*)d_out;

    unsigned short* projT = (unsigned short*)d_ws;          // 128*1024 bf16
    unsigned short* tMat  = projT + 128 * 1024;             // 16384*128 bf16
    float* sqn = (float*)(tMat + 16384 * 128);              // 16384 f32

    hipLaunchKernelGGL(transpose_proj, dim3(32),  dim3(256), 0, stream, proj, projT);
    hipLaunchKernelGGL(gemm_t,         dim3(512), dim3(256), 0, stream, batch, projT, tMat, sqn);
    hipLaunchKernelGGL(dist_k,         dim3(512), dim3(256), 0, stream, tMat, sqn, out);
}

// Round 4
// 128.439 us; speedup vs baseline: 1.1739x; 1.1739x over previous
//
#include <hip/hip_runtime.h>
#include <hip/hip_bf16.h>

// Problem: B=32, L=512, D=1024, R=128
//   t = batch(16384x1024) @ proj(1024x128)          [bf16 MFMA, fp32 acc]
//   d[b,i,j] = ||t_i||^2 + ||t_j||^2 - 2 t_i.t_j,  clamp >= 0
//
// R4: R2/R3 proved the compiler will not hold register pipelines (VGPR 44->28,
// all pipes idle, 700 GB/s). Switch to the measured-reliable MLP mechanism:
// global_load_lds (register-free DMA queue) into FRAGMENT-NATIVE LDS blocks
// (each MFMA fragment = contiguous 1KB in lane order -> staging is base+lane*16
// exactly, reads are one conflict-free ds_read_b128, no addressing math).
// gemm_t: double-buffered LDS, 1 barrier/K-step. dist_k: one async volley,
// 1 barrier total.

typedef __attribute__((ext_vector_type(8))) short bf16x8;
typedef __attribute__((ext_vector_type(4))) float f32x4;

typedef __attribute__((address_space(3))) unsigned lds_u;
typedef __attribute__((address_space(1))) const unsigned gbl_u;

__device__ __forceinline__ void async16(void* lds, const void* g) {
    __builtin_amdgcn_global_load_lds((gbl_u*)(unsigned long long)g,
                                     (lds_u*)(unsigned)(unsigned long long)lds,
                                     16, 0, 0);
}

__device__ __forceinline__ unsigned short f2bf(float f) {
    unsigned u = __float_as_uint(f);
    unsigned r = (u + 0x7fffu + ((u >> 16) & 1u)) >> 16;   // RNE
    return (unsigned short)r;
}
__device__ __forceinline__ float bf2f(unsigned short h) {
    return __uint_as_float(((unsigned)h) << 16);
}
__device__ __forceinline__ bf16x8 pack8(float4 x, float4 y) {
    bf16x8 r;
    r[0] = (short)f2bf(x.x); r[1] = (short)f2bf(x.y);
    r[2] = (short)f2bf(x.z); r[3] = (short)f2bf(x.w);
    r[4] = (short)f2bf(y.x); r[5] = (short)f2bf(y.y);
    r[6] = (short)f2bf(y.z); r[7] = (short)f2bf(y.w);
    return r;
}

// ---------------- kernel 0: proj (1024x128 f32) -> projT (128x1024 bf16) ----------------
__global__ __launch_bounds__(256) void transpose_proj(const float* __restrict__ proj,
                                                      unsigned short* __restrict__ projT) {
    __shared__ unsigned short TsT[128][40];
    const int k0 = blockIdx.x * 32;
    const int t = threadIdx.x;
    const int kl = t >> 3;
    const int seg = t & 7;
    const float* src = proj + (k0 + kl) * 128 + seg * 16;
#pragma unroll
    for (int i = 0; i < 4; ++i) {
        float4 v = *(const float4*)(src + 4 * i);
        int c = seg * 16 + 4 * i;
        TsT[c + 0][kl] = f2bf(v.x);
        TsT[c + 1][kl] = f2bf(v.y);
        TsT[c + 2][kl] = f2bf(v.z);
        TsT[c + 3][kl] = f2bf(v.w);
    }
    __syncthreads();
    const int r = t >> 1, h = t & 1;
#pragma unroll
    for (int i = 0; i < 2; ++i) {
        *(uint4*)(projT + r * 1024 + k0 + h * 16 + 8 * i) =
            *(const uint4*)&TsT[r][h * 16 + 8 * i];
    }
}

// ---------------- kernel 1: t = batch @ proj  (M=16384, N=128, K=1024) ----------------
// grid 512 (M-tile 32), block 256 = 4 waves (2M x 2N), BK=64, LDS double-buffer.
// LDS buf layout (24KB): A fp32 frag-blocks [wm(2)][h(2)][part(2)] 8x1KB,
//                        B bf16 frag-blocks bi=wn*8+fn*2+h 16x1KB at +8KB.
__global__ __launch_bounds__(256) void gemm_t(const float* __restrict__ batch,
                                              const unsigned short* __restrict__ projT,
                                              unsigned short* __restrict__ tOut,
                                              float* __restrict__ sqn) {
    __shared__ unsigned char Ls[2][24 * 1024];
    __shared__ float sqpart[2][2][16];

    const int t = threadIdx.x;
    const int wave = t >> 6, lane = t & 63;
    const int wm = wave >> 1, wn = wave & 1;
    const int quad = lane >> 4, l15 = lane & 15;
    const int m0 = blockIdx.x * 32;

    // staging sources for this thread's role:
    // A calls c=0,1: wave w stages block id (w*2+c) = ((wm_s*2+h_s)*2+part):
    //   wm_s=w>>1, h_s=w&1, part=c; lane l -> row l15, floats quad*8 + c*4
    const float* aSrc = batch + (m0 + (wave >> 1) * 16 + l15) * 1024
                      + (wave & 1) * 32 + quad * 8;
    // B calls c=0..3: bi = c*4 + wave; (wn_s=bi>>3, fn_s=(bi>>1)&3, h_s=bi&1)
    const unsigned short* bSrc[4];
#pragma unroll
    for (int c = 0; c < 4; ++c) {
        int bi = c * 4 + wave;
        bSrc[c] = projT + ((bi >> 3) * 64 + ((bi >> 1) & 3) * 16 + l15) * 1024
                + (bi & 1) * 32 + quad * 8;
    }

    f32x4 acc[4] = {};

    auto stage = [&](int buf, int kk) {
        unsigned char* base = &Ls[buf][0];
        async16(base + (wave * 2 + 0) * 1024 + lane * 16, aSrc + kk);
        async16(base + (wave * 2 + 1) * 1024 + lane * 16, aSrc + kk + 4);
#pragma unroll
        for (int c = 0; c < 4; ++c) {
            int bi = c * 4 + wave;
            async16(base + 8192 + bi * 1024 + lane * 16, bSrc[c] + kk);
        }
    };

    stage(0, 0);
#pragma unroll
    for (int s = 0; s < 16; ++s) {
        __syncthreads();                      // drains vmcnt -> buf[s&1] ready
        if (s < 15) stage((s + 1) & 1, (s + 1) * 64);
        const unsigned char* base = &Ls[s & 1][0];
        bf16x8 af[2];
#pragma unroll
        for (int h = 0; h < 2; ++h) {
            float4 f0 = *(const float4*)(base + ((wm * 2 + h) * 2 + 0) * 1024 + lane * 16);
            float4 f1 = *(const float4*)(base + ((wm * 2 + h) * 2 + 1) * 1024 + lane * 16);
            af[h] = pack8(f0, f1);
        }
#pragma unroll
        for (int fn = 0; fn < 4; ++fn) {
#pragma unroll
            for (int h = 0; h < 2; ++h) {
                int bi = wn * 8 + fn * 2 + h;
                bf16x8 bfr = *(const bf16x8*)(base + 8192 + bi * 1024 + lane * 16);
                acc[fn] = __builtin_amdgcn_mfma_f32_16x16x32_bf16(af[h], bfr, acc[fn], 0, 0, 0);
            }
        }
    }

    // epilogue: write t (bf16), accumulate row sq-norms from ROUNDED values
    float p[4] = {0.f, 0.f, 0.f, 0.f};
#pragma unroll
    for (int fn = 0; fn < 4; ++fn) {
        int col = wn * 64 + fn * 16 + l15;
#pragma unroll
        for (int reg = 0; reg < 4; ++reg) {
            int row = m0 + wm * 16 + quad * 4 + reg;
            unsigned short hb = f2bf(acc[fn][reg]);
            tOut[row * 128 + col] = hb;
            float fv = bf2f(hb);
            p[reg] += fv * fv;
        }
    }
#pragma unroll
    for (int off = 1; off < 16; off <<= 1) {
#pragma unroll
        for (int reg = 0; reg < 4; ++reg) p[reg] += __shfl_xor(p[reg], off);
    }
    if (l15 == 0) {
#pragma unroll
        for (int reg = 0; reg < 4; ++reg) sqpart[wm][wn][quad * 4 + reg] = p[reg];
    }
    __syncthreads();
    if (t < 32) {
        int wmi = t >> 4, ridx = t & 15;
        sqn[m0 + wmi * 16 + ridx] = sqpart[wmi][0][ridx] + sqpart[wmi][1][ridx];
    }
}

// ---------------- kernel 2: d[b,i,j] = sq_i + sq_j - 2 * t_i . t_j, clamped ----------------
// grid 512 = 32 batches x 4x4 tiles of 128. Transposed tile (A=t_j rows per wave,
// B=t_i shared) -> float4 stores. All fragments staged frag-native via async DMA,
// ONE barrier. LDS 64KB: A blocks (w*8+fm*4+ksi)*1KB, B blocks 32KB + (fn*4+ksi)*1KB.
__global__ __launch_bounds__(256) void dist_k(const unsigned short* __restrict__ tMat,
                                              const float* __restrict__ sqn,
                                              float* __restrict__ out) {
    __shared__ unsigned char Ls[64 * 1024];

    const int bx = blockIdx.x;
    const int b = bx >> 4, it = (bx >> 2) & 3, jt = bx & 3;
    const int i0 = it * 128, j0 = jt * 128;
    const int t = threadIdx.x;
    const int wave = t >> 6, lane = t & 63;
    const int quad = lane >> 4, l15 = lane & 15;

    // A-frags (wave-private): 8 calls, block (wave, fm=c>>2, ksi=c&3)
    const unsigned short* aS = tMat + (b * 512 + j0 + wave * 32 + l15) * 128 + quad * 8;
#pragma unroll
    for (int c = 0; c < 8; ++c)
        async16(&Ls[(wave * 8 + c) * 1024 + lane * 16],
                aS + (c >> 2) * 16 * 128 + (c & 3) * 32);

    // B-frags (shared): 8 calls, bi = c*4 + wave -> (fn=bi>>2, ksi=bi&3)
    const unsigned short* bS = tMat + (b * 512 + i0 + l15) * 128 + quad * 8;
#pragma unroll
    for (int c = 0; c < 8; ++c) {
        int bi = c * 4 + wave;
        async16(&Ls[32768 + bi * 1024 + lane * 16],
                bS + (bi >> 2) * 16 * 128 + (bi & 3) * 32);
    }

    // sq-norm scalars (in registers, overlapped with DMA)
    const float* sqb = sqn + b * 512;
    float sqj_[2][4], sqi_[8];
#pragma unroll
    for (int fm = 0; fm < 2; ++fm)
#pragma unroll
        for (int reg = 0; reg < 4; ++reg)
            sqj_[fm][reg] = sqb[j0 + wave * 32 + fm * 16 + quad * 4 + reg];
#pragma unroll
    for (int fn = 0; fn < 8; ++fn)
        sqi_[fn] = sqb[i0 + fn * 16 + l15];

    __syncthreads();                          // single drain

    f32x4 acc[2][8] = {};
#pragma unroll
    for (int ksi = 0; ksi < 4; ++ksi) {
        bf16x8 af[2];
#pragma unroll
        for (int fm = 0; fm < 2; ++fm)
            af[fm] = *(const bf16x8*)&Ls[(wave * 8 + fm * 4 + ksi) * 1024 + lane * 16];
#pragma unroll
        for (int fn = 0; fn < 8; ++fn) {
            bf16x8 bfr = *(const bf16x8*)&Ls[32768 + (fn * 4 + ksi) * 1024 + lane * 16];
#pragma unroll
            for (int fm = 0; fm < 2; ++fm)
                acc[fm][fn] = __builtin_amdgcn_mfma_f32_16x16x32_bf16(af[fm], bfr, acc[fm][fn], 0, 0, 0);
        }
    }

    // epilogue: d = sq_i + sq_j - 2c, clamp, float4 stores (j-contiguous)
    float* obase = out + (size_t)b * 512 * 512;
#pragma unroll
    for (int fn = 0; fn < 8; ++fn) {
        const int i = i0 + fn * 16 + l15;
        float* orow = obase + (size_t)i * 512 + j0;
        const float si = sqi_[fn];
#pragma unroll
        for (int fm = 0; fm < 2; ++fm) {
            float4 v;
            v.x = fmaxf(si + sqj_[fm][0] - 2.0f * acc[fm][fn][0], 0.0f);
            v.y = fmaxf(si + sqj_[fm][1] - 2.0f * acc[fm][fn][1], 0.0f);
            v.z = fmaxf(si + sqj_[fm][2] - 2.0f * acc[fm][fn][2], 0.0f);
            v.w = fmaxf(si + sqj_[fm][3] - 2.0f * acc[fm][fn][3], 0.0f);
            *(float4*)(orow + wave * 32 + fm * 16 + quad * 4) = v;
        }
    }
}

extern "C" void kernel_launch(void* const* d_in, const int* in_sizes, int n_in,
                              void* d_out, int out_size, void* d_ws, size_t ws_size,
                              hipStream_t stream) {
    (void)in_sizes; (void)n_in; (void)out_size; (void)ws_size;
    const float* batch = (const float*)d_in[0];
    const float* proj  = (const float*)d_in[1];
    float* out = (float*)d_out;

    unsigned short* projT = (unsigned short*)d_ws;          // 128*1024 bf16
    unsigned short* tMat  = projT + 128 * 1024;             // 16384*128 bf16
    float* sqn = (float*)(tMat + 16384 * 128);              // 16384 f32

    hipLaunchKernelGGL(transpose_proj, dim3(32),  dim3(256), 0, stream, proj, projT);
    hipLaunchKernelGGL(gemm_t,         dim3(512), dim3(256), 0, stream, batch, projT, tMat, sqn);
    hipLaunchKernelGGL(dist_k,         dim3(512), dim3(256), 0, stream, tMat, sqn, out);
}